// Round 1
// baseline (91.029 us; speedup 1.0000x reference)
//
#include <hip/hip_runtime.h>

#pragma clang fp contract(off)

namespace {

constexpr int kT  = 2;
constexpr int kR  = 2;
constexpr int kP  = 2048;
constexpr int kNT = 400;
constexpr float kEps   = 1e-6f;
constexpr float kHitTh = 0.999f;

constexpr int kNumPaths  = kT * kR * kP;      // 8192
constexpr int kFpFloats  = kNumPaths * 12;    // 98304
constexpr int kObjFloats = kNumPaths * 4;     // 32768

__device__ inline void cross3(const float a[3], const float b[3], float o[3]) {
    o[0] = a[1] * b[2] - a[2] * b[1];
    o[1] = a[2] * b[0] - a[0] * b[2];
    o[2] = a[0] * b[1] - a[1] * b[0];
}
__device__ inline float dot3(const float a[3], const float b[3]) {
    return a[0] * b[0] + a[1] * b[1] + a[2] * b[2];
}

__global__ __launch_bounds__(256)
void tri_scene_kernel(const float* __restrict__ tx,
                      const float* __restrict__ rx,
                      const float* __restrict__ verts,
                      const float* __restrict__ normals,
                      const int*   __restrict__ tris,
                      const int*   __restrict__ pcs,
                      float*       __restrict__ out)
{
    // Stage all triangles as (v0, e1, e2) in LDS: 400*9*4 = 14.4 KB.
    __shared__ float sV0[kNT][3];
    __shared__ float sE1[kNT][3];
    __shared__ float sE2[kNT][3];

    for (int j = threadIdx.x; j < kNT; j += blockDim.x) {
        int i0 = tris[3 * j + 0], i1 = tris[3 * j + 1], i2 = tris[3 * j + 2];
        float ax = verts[3 * i0 + 0], ay = verts[3 * i0 + 1], az = verts[3 * i0 + 2];
        float bx = verts[3 * i1 + 0], by = verts[3 * i1 + 1], bz = verts[3 * i1 + 2];
        float cx = verts[3 * i2 + 0], cy = verts[3 * i2 + 1], cz = verts[3 * i2 + 2];
        sV0[j][0] = ax;      sV0[j][1] = ay;      sV0[j][2] = az;
        sE1[j][0] = bx - ax; sE1[j][1] = by - ay; sE1[j][2] = bz - az;
        sE2[j][0] = cx - ax; sE2[j][1] = cy - ay; sE2[j][2] = cz - az;
    }
    __syncthreads();

    const int lane = threadIdx.x & 63;
    const int L = blockIdx.x * 4 + (threadIdx.x >> 6);   // one wave per path
    const int tIdx = L / (kR * kP);
    const int rem  = L % (kR * kP);
    const int rIdx = rem / kP;
    const int p    = rem % kP;

    // full path points: fp[0]=tx, fp[1]=reflect pt 0, fp[2]=reflect pt 1, fp[3]=rx
    float fp[4][3];
    fp[0][0] = tx[3 * tIdx + 0]; fp[0][1] = tx[3 * tIdx + 1]; fp[0][2] = tx[3 * tIdx + 2];
    fp[3][0] = rx[3 * rIdx + 0]; fp[3][1] = rx[3 * rIdx + 1]; fp[3][2] = rx[3 * rIdx + 2];

    const int pcm[2] = { pcs[2 * p + 0], pcs[2 * p + 1] };

    // mirror triangle vertices + normals (wave-uniform loads)
    float tv[2][3][3];
    float mn[2][3];
    #pragma unroll
    for (int m = 0; m < 2; ++m) {
        int tc = pcm[m];
        int i0 = tris[3 * tc + 0], i1 = tris[3 * tc + 1], i2 = tris[3 * tc + 2];
        #pragma unroll
        for (int c = 0; c < 3; ++c) {
            tv[m][0][c] = verts[3 * i0 + c];
            tv[m][1][c] = verts[3 * i1 + c];
            tv[m][2][c] = verts[3 * i2 + c];
            mn[m][c]    = normals[3 * tc + c];
        }
    }

    // ---- image method (exact reference op order) ----
    float img0[3], img1[3];
    {
        float diff[3];
        #pragma unroll
        for (int c = 0; c < 3; ++c) diff[c] = fp[0][c] - tv[0][0][c];
        float d0 = dot3(diff, mn[0]);
        #pragma unroll
        for (int c = 0; c < 3; ++c) img0[c] = fp[0][c] - 2.0f * d0 * mn[0][c];
        #pragma unroll
        for (int c = 0; c < 3; ++c) diff[c] = img0[c] - tv[1][0][c];
        float d1 = dot3(diff, mn[1]);
        #pragma unroll
        for (int c = 0; c < 3; ++c) img1[c] = img0[c] - 2.0f * d1 * mn[1][c];
    }
    {
        float u[3], w[3];
        #pragma unroll
        for (int c = 0; c < 3; ++c) u[c] = fp[3][c] - img1[c];
        #pragma unroll
        for (int c = 0; c < 3; ++c) w[c] = tv[1][0][c] - img1[c];
        float tpar = dot3(w, mn[1]) / dot3(u, mn[1]);
        #pragma unroll
        for (int c = 0; c < 3; ++c) fp[2][c] = img1[c] + tpar * u[c];
        #pragma unroll
        for (int c = 0; c < 3; ++c) u[c] = fp[2][c] - img0[c];
        #pragma unroll
        for (int c = 0; c < 3; ++c) w[c] = tv[0][0][c] - img0[c];
        tpar = dot3(w, mn[0]) / dot3(u, mn[0]);
        #pragma unroll
        for (int c = 0; c < 3; ++c) fp[1][c] = img0[c] + tpar * u[c];
    }

    // ---- mask1: containment ----
    bool mask1 = true;
    #pragma unroll
    for (int m = 0; m < 2; ++m) {
        float u0[3], u1[3], u2[3], n0[3], n1[3], n2[3];
        #pragma unroll
        for (int c = 0; c < 3; ++c) {
            u0[c] = tv[m][0][c] - fp[1 + m][c];
            u1[c] = tv[m][1][c] - fp[1 + m][c];
            u2[c] = tv[m][2][c] - fp[1 + m][c];
        }
        cross3(u0, u1, n0); cross3(u1, u2, n1); cross3(u2, u0, n2);
        float d01 = dot3(n0, n1), d12 = dot3(n1, n2), d20 = dot3(n2, n0);
        mask1 = mask1 && (d01 >= 0.0f) && (d12 >= 0.0f) && (d20 >= 0.0f);
    }

    // ---- mask2: consecutive same side ----
    bool mask2 = true;
    #pragma unroll
    for (int m = 0; m < 2; ++m) {
        float a[3], b[3];
        #pragma unroll
        for (int c = 0; c < 3; ++c) {
            a[c] = fp[m][c]     - tv[m][0][c];
            b[c] = fp[m + 2][c] - tv[m][0][c];
        }
        float dp = dot3(a, mn[m]);
        float dn = dot3(b, mn[m]);
        mask2 = mask2 && (dp * dn >= 0.0f);
    }

    // ---- mask3: Moller-Trumbore vs all triangles, lanes split triangles ----
    bool hitLocal = false;
    #pragma unroll
    for (int s = 0; s < 3; ++s) {
        float ro[3], rd[3];
        #pragma unroll
        for (int c = 0; c < 3; ++c) {
            ro[c] = fp[s][c];
            rd[c] = fp[s + 1][c] - fp[s][c];
        }
        for (int j = lane; j < kNT; j += 64) {
            float v0[3] = { sV0[j][0], sV0[j][1], sV0[j][2] };
            float e1[3] = { sE1[j][0], sE1[j][1], sE1[j][2] };
            float e2[3] = { sE2[j][0], sE2[j][1], sE2[j][2] };
            float h[3]; cross3(rd, e2, h);
            float a = dot3(e1, h);
            float f = 1.0f / a;
            float sv[3];
            #pragma unroll
            for (int c = 0; c < 3; ++c) sv[c] = ro[c] - v0[c];
            float uu = f * dot3(sv, h);
            float q[3]; cross3(sv, e1, q);
            float vv = f * dot3(rd, q);
            float tt = f * dot3(e2, q);
            bool hit = (fabsf(a) > kEps) && (uu >= 0.0f) && (uu <= 1.0f)
                    && (vv >= 0.0f) && (uu + vv <= 1.0f)
                    && (tt > kEps) && (tt < kHitTh);
            hitLocal = hitLocal || hit;
        }
    }
    const bool anyhit = __any(hitLocal ? 1 : 0) != 0;
    const bool mask = mask1 && mask2 && !anyhit;

    // ---- writes (lane 0 of each wave) ----
    if (lane == 0) {
        float* fpOut = out + (size_t)L * 12;
        #pragma unroll
        for (int pt = 0; pt < 4; ++pt)
            #pragma unroll
            for (int c = 0; c < 3; ++c)
                fpOut[pt * 3 + c] = fp[pt][c];
        float* objOut = out + kFpFloats + (size_t)L * 4;
        objOut[0] = (float)tIdx;
        objOut[1] = (float)pcm[0];
        objOut[2] = (float)pcm[1];
        objOut[3] = (float)rIdx;
        out[kFpFloats + kObjFloats + L] = mask ? 1.0f : 0.0f;
    }
}

} // namespace

extern "C" void kernel_launch(void* const* d_in, const int* in_sizes, int n_in,
                              void* d_out, int out_size, void* d_ws, size_t ws_size,
                              hipStream_t stream)
{
    const float* tx      = (const float*)d_in[0];
    const float* rx      = (const float*)d_in[1];
    const float* verts   = (const float*)d_in[2];
    const float* normals = (const float*)d_in[3];
    const int*   tris    = (const int*)d_in[4];
    const int*   pcs     = (const int*)d_in[5];
    float* out = (float*)d_out;

    dim3 grid(kNumPaths / 4);   // 2048 blocks, 4 waves (paths) per block
    dim3 block(256);
    hipLaunchKernelGGL(tri_scene_kernel, grid, block, 0, stream,
                       tx, rx, verts, normals, tris, pcs, out);
}

// Round 4
// 85.165 us; speedup vs baseline: 1.0689x; 1.0689x over previous
//
#include <hip/hip_runtime.h>

#pragma clang fp contract(off)

namespace {

constexpr int kT  = 2;
constexpr int kR  = 2;
constexpr int kP  = 2048;
constexpr int kNT = 400;
constexpr float kEps   = 1e-6f;
constexpr float kHitTh = 0.999f;

constexpr int kNumPaths  = kT * kR * kP;      // 8192
constexpr int kFpFloats  = kNumPaths * 12;    // 98304
constexpr int kObjFloats = kNumPaths * 4;     // 32768

// ws layout (float/int indices):
//   tri pre-compute: [0, 448*12) floats, per tri j: v0@+0..2, e1@+4..6, e2@+8..10
//   mask12:          int[kNumPaths] at float-offset kWsMaskOff
constexpr int kTriStride = 12;
constexpr int kTriPad    = 448;               // padded so OOB j<448 reads stay in ws
constexpr int kWsMaskOff = kTriPad * kTriStride;

__device__ inline void cross3(const float a[3], const float b[3], float o[3]) {
    o[0] = a[1] * b[2] - a[2] * b[1];
    o[1] = a[2] * b[0] - a[0] * b[2];
    o[2] = a[0] * b[1] - a[1] * b[0];
}
__device__ inline float dot3(const float a[3], const float b[3]) {
    return a[0] * b[0] + a[1] * b[1] + a[2] * b[2];
}

// ---------------- Kernel A: per-path setup (1 thread/path) + triangle precompute
__global__ __launch_bounds__(256)
void setup_kernel(const float* __restrict__ tx,
                  const float* __restrict__ rx,
                  const float* __restrict__ verts,
                  const float* __restrict__ normals,
                  const int*   __restrict__ tris,
                  const int*   __restrict__ pcs,
                  float*       __restrict__ out,
                  float*       __restrict__ wsTri,
                  int*         __restrict__ wsMask)
{
    const int tid = blockIdx.x * 256 + threadIdx.x;

    if (tid < kNumPaths) {
        const int L    = tid;
        const int tIdx = L / (kR * kP);
        const int rem  = L % (kR * kP);
        const int rIdx = rem / kP;
        const int p    = rem % kP;

        float fp[4][3];
        fp[0][0] = tx[3 * tIdx + 0]; fp[0][1] = tx[3 * tIdx + 1]; fp[0][2] = tx[3 * tIdx + 2];
        fp[3][0] = rx[3 * rIdx + 0]; fp[3][1] = rx[3 * rIdx + 1]; fp[3][2] = rx[3 * rIdx + 2];

        const int pcm[2] = { pcs[2 * p + 0], pcs[2 * p + 1] };

        float tv[2][3][3];
        float mn[2][3];
        #pragma unroll
        for (int m = 0; m < 2; ++m) {
            int tc = pcm[m];
            int i0 = tris[3 * tc + 0], i1 = tris[3 * tc + 1], i2 = tris[3 * tc + 2];
            #pragma unroll
            for (int c = 0; c < 3; ++c) {
                tv[m][0][c] = verts[3 * i0 + c];
                tv[m][1][c] = verts[3 * i1 + c];
                tv[m][2][c] = verts[3 * i2 + c];
                mn[m][c]    = normals[3 * tc + c];
            }
        }

        // ---- image method (exact reference op order) ----
        float img0[3], img1[3];
        {
            float diff[3];
            #pragma unroll
            for (int c = 0; c < 3; ++c) diff[c] = fp[0][c] - tv[0][0][c];
            float d0 = dot3(diff, mn[0]);
            #pragma unroll
            for (int c = 0; c < 3; ++c) img0[c] = fp[0][c] - 2.0f * d0 * mn[0][c];
            #pragma unroll
            for (int c = 0; c < 3; ++c) diff[c] = img0[c] - tv[1][0][c];
            float d1 = dot3(diff, mn[1]);
            #pragma unroll
            for (int c = 0; c < 3; ++c) img1[c] = img0[c] - 2.0f * d1 * mn[1][c];
        }
        {
            float u[3], w[3];
            #pragma unroll
            for (int c = 0; c < 3; ++c) u[c] = fp[3][c] - img1[c];
            #pragma unroll
            for (int c = 0; c < 3; ++c) w[c] = tv[1][0][c] - img1[c];
            float tpar = dot3(w, mn[1]) / dot3(u, mn[1]);
            #pragma unroll
            for (int c = 0; c < 3; ++c) fp[2][c] = img1[c] + tpar * u[c];
            #pragma unroll
            for (int c = 0; c < 3; ++c) u[c] = fp[2][c] - img0[c];
            #pragma unroll
            for (int c = 0; c < 3; ++c) w[c] = tv[0][0][c] - img0[c];
            tpar = dot3(w, mn[0]) / dot3(u, mn[0]);
            #pragma unroll
            for (int c = 0; c < 3; ++c) fp[1][c] = img0[c] + tpar * u[c];
        }

        // ---- mask1: containment ----
        bool mask1 = true;
        #pragma unroll
        for (int m = 0; m < 2; ++m) {
            float u0[3], u1[3], u2[3], n0[3], n1[3], n2[3];
            #pragma unroll
            for (int c = 0; c < 3; ++c) {
                u0[c] = tv[m][0][c] - fp[1 + m][c];
                u1[c] = tv[m][1][c] - fp[1 + m][c];
                u2[c] = tv[m][2][c] - fp[1 + m][c];
            }
            cross3(u0, u1, n0); cross3(u1, u2, n1); cross3(u2, u0, n2);
            float d01 = dot3(n0, n1), d12 = dot3(n1, n2), d20 = dot3(n2, n0);
            mask1 = mask1 && (d01 >= 0.0f) && (d12 >= 0.0f) && (d20 >= 0.0f);
        }

        // ---- mask2: consecutive same side ----
        bool mask2 = true;
        #pragma unroll
        for (int m = 0; m < 2; ++m) {
            float a[3], b[3];
            #pragma unroll
            for (int c = 0; c < 3; ++c) {
                a[c] = fp[m][c]     - tv[m][0][c];
                b[c] = fp[m + 2][c] - tv[m][0][c];
            }
            float dp = dot3(a, mn[m]);
            float dn = dot3(b, mn[m]);
            mask2 = mask2 && (dp * dn >= 0.0f);
        }

        // ---- outputs ----
        float* fpOut = out + (size_t)L * 12;
        #pragma unroll
        for (int pt = 0; pt < 4; ++pt)
            #pragma unroll
            for (int c = 0; c < 3; ++c)
                fpOut[pt * 3 + c] = fp[pt][c];
        float* objOut = out + kFpFloats + (size_t)L * 4;
        objOut[0] = (float)tIdx;
        objOut[1] = (float)pcm[0];
        objOut[2] = (float)pcm[1];
        objOut[3] = (float)rIdx;
        wsMask[L] = (mask1 && mask2) ? 1 : 0;
    } else {
        const int j = tid - kNumPaths;
        if (j < kNT) {
            int i0 = tris[3 * j + 0], i1 = tris[3 * j + 1], i2 = tris[3 * j + 2];
            float ax = verts[3 * i0 + 0], ay = verts[3 * i0 + 1], az = verts[3 * i0 + 2];
            float bx = verts[3 * i1 + 0], by = verts[3 * i1 + 1], bz = verts[3 * i1 + 2];
            float cx = verts[3 * i2 + 0], cy = verts[3 * i2 + 1], cz = verts[3 * i2 + 2];
            float* t = wsTri + j * kTriStride;
            t[0]  = ax;      t[1]  = ay;      t[2]  = az;      t[3]  = 0.0f;
            t[4]  = bx - ax; t[5]  = by - ay; t[6]  = bz - az; t[7]  = 0.0f;
            t[8]  = cx - ax; t[9]  = cy - ay; t[10] = cz - az; t[11] = 0.0f;
        }
    }
}

// ---------------- Kernel B: Moller-Trumbore occlusion, 1 wave/path, early exit
__global__ __launch_bounds__(256)
void mt_kernel(const float* __restrict__ wsTri,
               const int*   __restrict__ wsMask,
               float*       __restrict__ out)
{
    const int lane = threadIdx.x & 63;
    const int L = blockIdx.x * 4 + (threadIdx.x >> 6);

    const float4* fp4 = reinterpret_cast<const float4*>(out + (size_t)L * 12);
    float4 fa = fp4[0], fb = fp4[1], fc = fp4[2];
    const float p0x = fa.x, p0y = fa.y, p0z = fa.z;
    const float p1x = fa.w, p1y = fb.x, p1z = fb.y;
    const float p2x = fb.z, p2y = fb.w, p2z = fc.x;
    const float p3x = fc.y, p3y = fc.z, p3z = fc.w;

    bool anyhit = false;
    #pragma unroll
    for (int s = 0; s < 3; ++s) {
        if (anyhit) break;
        float ro[3], rd[3];
        if (s == 0) {
            ro[0] = p0x; ro[1] = p0y; ro[2] = p0z;
            rd[0] = p1x - p0x; rd[1] = p1y - p0y; rd[2] = p1z - p0z;
        } else if (s == 1) {
            ro[0] = p1x; ro[1] = p1y; ro[2] = p1z;
            rd[0] = p2x - p1x; rd[1] = p2y - p1y; rd[2] = p2z - p1z;
        } else {
            ro[0] = p2x; ro[1] = p2y; ro[2] = p2z;
            rd[0] = p3x - p2x; rd[1] = p3y - p2y; rd[2] = p3z - p2z;
        }

        // 7 uniform chunks of 64 triangles; all lanes stay active so the
        // __any() early-exit branch is wave-uniform.
        for (int jb = 0; jb < 7; ++jb) {
            const int j = jb * 64 + lane;
            const bool valid = (j < kNT);
            const float4* t = reinterpret_cast<const float4*>(wsTri + j * kTriStride);
            float4 t0 = t[0], t1 = t[1], t2 = t[2];   // v0, e1, e2 (padded reads stay in ws)
            float v0[3] = { t0.x, t0.y, t0.z };
            float e1[3] = { t1.x, t1.y, t1.z };
            float e2[3] = { t2.x, t2.y, t2.z };
            float h[3]; cross3(rd, e2, h);
            float a = dot3(e1, h);
            float f = 1.0f / a;
            float sv[3];
            #pragma unroll
            for (int c = 0; c < 3; ++c) sv[c] = ro[c] - v0[c];
            float uu = f * dot3(sv, h);
            float q[3]; cross3(sv, e1, q);
            float vv = f * dot3(rd, q);
            float tt = f * dot3(e2, q);
            bool hit = valid
                    && (fabsf(a) > kEps) && (uu >= 0.0f) && (uu <= 1.0f)
                    && (vv >= 0.0f) && (uu + vv <= 1.0f)
                    && (tt > kEps) && (tt < kHitTh);
            if (__any(hit ? 1 : 0)) { anyhit = true; break; }
        }
    }

    if (lane == 0) {
        const bool mask = (wsMask[L] != 0) && !anyhit;
        out[kFpFloats + kObjFloats + L] = mask ? 1.0f : 0.0f;
    }
}

} // namespace

extern "C" void kernel_launch(void* const* d_in, const int* in_sizes, int n_in,
                              void* d_out, int out_size, void* d_ws, size_t ws_size,
                              hipStream_t stream)
{
    const float* tx      = (const float*)d_in[0];
    const float* rx      = (const float*)d_in[1];
    const float* verts   = (const float*)d_in[2];
    const float* normals = (const float*)d_in[3];
    const int*   tris    = (const int*)d_in[4];
    const int*   pcs     = (const int*)d_in[5];
    float* out   = (float*)d_out;
    float* wsTri = (float*)d_ws;
    int*   wsMask = (int*)d_ws + kWsMaskOff;

    // Kernel A: 8192 path-setup threads + 400 triangle-precompute threads
    dim3 gridA((kNumPaths + kNT + 255) / 256);  // 34 blocks
    hipLaunchKernelGGL(setup_kernel, gridA, dim3(256), 0, stream,
                       tx, rx, verts, normals, tris, pcs, out, wsTri, wsMask);

    // Kernel B: one wave per path
    dim3 gridB(kNumPaths / 4);                  // 2048 blocks
    hipLaunchKernelGGL(mt_kernel, gridB, dim3(256), 0, stream,
                       wsTri, wsMask, out);
}

// Round 5
// 69.116 us; speedup vs baseline: 1.3170x; 1.2322x over previous
//
#include <hip/hip_runtime.h>

#pragma clang fp contract(off)

namespace {

constexpr int kT  = 2;
constexpr int kR  = 2;
constexpr int kP  = 2048;
constexpr int kNT = 400;
constexpr float kEps   = 1e-6f;
constexpr float kHitTh = 0.999f;

constexpr int kNumPaths  = kT * kR * kP;      // 8192
constexpr int kFpFloats  = kNumPaths * 12;    // 98304
constexpr int kObjFloats = kNumPaths * 4;     // 32768

// ws layout (float/int indices):
//   tri pre-compute: [0, 448*12) floats, per tri j: v0@+0..2, e1@+4..6, e2@+8..10
//   mask12:          int[kNumPaths] at float-offset kWsMaskOff
constexpr int kTriStride = 12;
constexpr int kTriPad    = 448;               // padded so OOB j<448 reads stay in ws
constexpr int kWsMaskOff = kTriPad * kTriStride;

__device__ inline void cross3(const float a[3], const float b[3], float o[3]) {
    o[0] = a[1] * b[2] - a[2] * b[1];
    o[1] = a[2] * b[0] - a[0] * b[2];
    o[2] = a[0] * b[1] - a[1] * b[0];
}
__device__ inline float dot3(const float a[3], const float b[3]) {
    return a[0] * b[0] + a[1] * b[1] + a[2] * b[2];
}

// ---------------- Kernel A: per-path setup (1 thread/path) + triangle precompute
__global__ __launch_bounds__(256)
void setup_kernel(const float* __restrict__ tx,
                  const float* __restrict__ rx,
                  const float* __restrict__ verts,
                  const float* __restrict__ normals,
                  const int*   __restrict__ tris,
                  const int*   __restrict__ pcs,
                  float*       __restrict__ out,
                  float*       __restrict__ wsTri,
                  int*         __restrict__ wsMask)
{
    const int tid = blockIdx.x * 256 + threadIdx.x;

    if (tid < kNumPaths) {
        const int L    = tid;
        const int tIdx = L / (kR * kP);
        const int rem  = L % (kR * kP);
        const int rIdx = rem / kP;
        const int p    = rem % kP;

        float fp[4][3];
        fp[0][0] = tx[3 * tIdx + 0]; fp[0][1] = tx[3 * tIdx + 1]; fp[0][2] = tx[3 * tIdx + 2];
        fp[3][0] = rx[3 * rIdx + 0]; fp[3][1] = rx[3 * rIdx + 1]; fp[3][2] = rx[3 * rIdx + 2];

        const int pcm[2] = { pcs[2 * p + 0], pcs[2 * p + 1] };

        float tv[2][3][3];
        float mn[2][3];
        #pragma unroll
        for (int m = 0; m < 2; ++m) {
            int tc = pcm[m];
            int i0 = tris[3 * tc + 0], i1 = tris[3 * tc + 1], i2 = tris[3 * tc + 2];
            #pragma unroll
            for (int c = 0; c < 3; ++c) {
                tv[m][0][c] = verts[3 * i0 + c];
                tv[m][1][c] = verts[3 * i1 + c];
                tv[m][2][c] = verts[3 * i2 + c];
                mn[m][c]    = normals[3 * tc + c];
            }
        }

        // ---- image method (exact reference op order) ----
        float img0[3], img1[3];
        {
            float diff[3];
            #pragma unroll
            for (int c = 0; c < 3; ++c) diff[c] = fp[0][c] - tv[0][0][c];
            float d0 = dot3(diff, mn[0]);
            #pragma unroll
            for (int c = 0; c < 3; ++c) img0[c] = fp[0][c] - 2.0f * d0 * mn[0][c];
            #pragma unroll
            for (int c = 0; c < 3; ++c) diff[c] = img0[c] - tv[1][0][c];
            float d1 = dot3(diff, mn[1]);
            #pragma unroll
            for (int c = 0; c < 3; ++c) img1[c] = img0[c] - 2.0f * d1 * mn[1][c];
        }
        {
            float u[3], w[3];
            #pragma unroll
            for (int c = 0; c < 3; ++c) u[c] = fp[3][c] - img1[c];
            #pragma unroll
            for (int c = 0; c < 3; ++c) w[c] = tv[1][0][c] - img1[c];
            float tpar = dot3(w, mn[1]) / dot3(u, mn[1]);
            #pragma unroll
            for (int c = 0; c < 3; ++c) fp[2][c] = img1[c] + tpar * u[c];
            #pragma unroll
            for (int c = 0; c < 3; ++c) u[c] = fp[2][c] - img0[c];
            #pragma unroll
            for (int c = 0; c < 3; ++c) w[c] = tv[0][0][c] - img0[c];
            tpar = dot3(w, mn[0]) / dot3(u, mn[0]);
            #pragma unroll
            for (int c = 0; c < 3; ++c) fp[1][c] = img0[c] + tpar * u[c];
        }

        // ---- mask1: containment ----
        bool mask1 = true;
        #pragma unroll
        for (int m = 0; m < 2; ++m) {
            float u0[3], u1[3], u2[3], n0[3], n1[3], n2[3];
            #pragma unroll
            for (int c = 0; c < 3; ++c) {
                u0[c] = tv[m][0][c] - fp[1 + m][c];
                u1[c] = tv[m][1][c] - fp[1 + m][c];
                u2[c] = tv[m][2][c] - fp[1 + m][c];
            }
            cross3(u0, u1, n0); cross3(u1, u2, n1); cross3(u2, u0, n2);
            float d01 = dot3(n0, n1), d12 = dot3(n1, n2), d20 = dot3(n2, n0);
            mask1 = mask1 && (d01 >= 0.0f) && (d12 >= 0.0f) && (d20 >= 0.0f);
        }

        // ---- mask2: consecutive same side ----
        bool mask2 = true;
        #pragma unroll
        for (int m = 0; m < 2; ++m) {
            float a[3], b[3];
            #pragma unroll
            for (int c = 0; c < 3; ++c) {
                a[c] = fp[m][c]     - tv[m][0][c];
                b[c] = fp[m + 2][c] - tv[m][0][c];
            }
            float dp = dot3(a, mn[m]);
            float dn = dot3(b, mn[m]);
            mask2 = mask2 && (dp * dn >= 0.0f);
        }

        // ---- outputs ----
        float* fpOut = out + (size_t)L * 12;
        #pragma unroll
        for (int pt = 0; pt < 4; ++pt)
            #pragma unroll
            for (int c = 0; c < 3; ++c)
                fpOut[pt * 3 + c] = fp[pt][c];
        float* objOut = out + kFpFloats + (size_t)L * 4;
        objOut[0] = (float)tIdx;
        objOut[1] = (float)pcm[0];
        objOut[2] = (float)pcm[1];
        objOut[3] = (float)rIdx;
        wsMask[L] = (mask1 && mask2) ? 1 : 0;
    } else {
        const int j = tid - kNumPaths;
        if (j < kNT) {
            int i0 = tris[3 * j + 0], i1 = tris[3 * j + 1], i2 = tris[3 * j + 2];
            float ax = verts[3 * i0 + 0], ay = verts[3 * i0 + 1], az = verts[3 * i0 + 2];
            float bx = verts[3 * i1 + 0], by = verts[3 * i1 + 1], bz = verts[3 * i1 + 2];
            float cx = verts[3 * i2 + 0], cy = verts[3 * i2 + 1], cz = verts[3 * i2 + 2];
            float* t = wsTri + j * kTriStride;
            t[0]  = ax;      t[1]  = ay;      t[2]  = az;      t[3]  = 0.0f;
            t[4]  = bx - ax; t[5]  = by - ay; t[6]  = bz - az; t[7]  = 0.0f;
            t[8]  = cx - ax; t[9]  = cy - ay; t[10] = cz - az; t[11] = 0.0f;
        }
    }
}

// ---------------- Kernel B: Moller-Trumbore occlusion, 1 wave/path.
// Gated on mask12: paths already failing containment/same-side skip the scan
// entirely (mask = mask12 && !anyhit == 0 regardless of anyhit).
__global__ __launch_bounds__(256)
void mt_kernel(const float* __restrict__ wsTri,
               const int*   __restrict__ wsMask,
               float*       __restrict__ out)
{
    const int lane = threadIdx.x & 63;
    const int L = blockIdx.x * 4 + (threadIdx.x >> 6);

    const int m12 = wsMask[L];   // wave-uniform broadcast load
    if (m12 == 0) {
        if (lane == 0) out[kFpFloats + kObjFloats + L] = 0.0f;
        return;
    }

    const float4* fp4 = reinterpret_cast<const float4*>(out + (size_t)L * 12);
    float4 fa = fp4[0], fb = fp4[1], fc = fp4[2];
    const float p0x = fa.x, p0y = fa.y, p0z = fa.z;
    const float p1x = fa.w, p1y = fb.x, p1z = fb.y;
    const float p2x = fb.z, p2y = fb.w, p2z = fc.x;
    const float p3x = fc.y, p3y = fc.z, p3z = fc.w;

    bool anyhit = false;
    #pragma unroll
    for (int s = 0; s < 3; ++s) {
        if (anyhit) break;
        float ro[3], rd[3];
        if (s == 0) {
            ro[0] = p0x; ro[1] = p0y; ro[2] = p0z;
            rd[0] = p1x - p0x; rd[1] = p1y - p0y; rd[2] = p1z - p0z;
        } else if (s == 1) {
            ro[0] = p1x; ro[1] = p1y; ro[2] = p1z;
            rd[0] = p2x - p1x; rd[1] = p2y - p1y; rd[2] = p2z - p1z;
        } else {
            ro[0] = p2x; ro[1] = p2y; ro[2] = p2z;
            rd[0] = p3x - p2x; rd[1] = p3y - p2y; rd[2] = p3z - p2z;
        }

        // 7 uniform chunks of 64 triangles; all lanes stay active so the
        // __any() early-exit branch is wave-uniform.
        for (int jb = 0; jb < 7; ++jb) {
            const int j = jb * 64 + lane;
            const bool valid = (j < kNT);
            const float4* t = reinterpret_cast<const float4*>(wsTri + j * kTriStride);
            float4 t0 = t[0], t1 = t[1], t2 = t[2];   // v0, e1, e2 (padded reads stay in ws)
            float v0[3] = { t0.x, t0.y, t0.z };
            float e1[3] = { t1.x, t1.y, t1.z };
            float e2[3] = { t2.x, t2.y, t2.z };
            float h[3]; cross3(rd, e2, h);
            float a = dot3(e1, h);
            float f = 1.0f / a;
            float sv[3];
            #pragma unroll
            for (int c = 0; c < 3; ++c) sv[c] = ro[c] - v0[c];
            float uu = f * dot3(sv, h);
            float q[3]; cross3(sv, e1, q);
            float vv = f * dot3(rd, q);
            float tt = f * dot3(e2, q);
            bool hit = valid
                    && (fabsf(a) > kEps) && (uu >= 0.0f) && (uu <= 1.0f)
                    && (vv >= 0.0f) && (uu + vv <= 1.0f)
                    && (tt > kEps) && (tt < kHitTh);
            if (__any(hit ? 1 : 0)) { anyhit = true; break; }
        }
    }

    if (lane == 0) {
        out[kFpFloats + kObjFloats + L] = anyhit ? 0.0f : 1.0f;
    }
}

} // namespace

extern "C" void kernel_launch(void* const* d_in, const int* in_sizes, int n_in,
                              void* d_out, int out_size, void* d_ws, size_t ws_size,
                              hipStream_t stream)
{
    const float* tx      = (const float*)d_in[0];
    const float* rx      = (const float*)d_in[1];
    const float* verts   = (const float*)d_in[2];
    const float* normals = (const float*)d_in[3];
    const int*   tris    = (const int*)d_in[4];
    const int*   pcs     = (const int*)d_in[5];
    float* out   = (float*)d_out;
    float* wsTri = (float*)d_ws;
    int*   wsMask = (int*)d_ws + kWsMaskOff;

    // Kernel A: 8192 path-setup threads + 400 triangle-precompute threads
    dim3 gridA((kNumPaths + kNT + 255) / 256);  // 34 blocks
    hipLaunchKernelGGL(setup_kernel, gridA, dim3(256), 0, stream,
                       tx, rx, verts, normals, tris, pcs, out, wsTri, wsMask);

    // Kernel B: one wave per path, gated on mask12
    dim3 gridB(kNumPaths / 4);                  // 2048 blocks
    hipLaunchKernelGGL(mt_kernel, gridB, dim3(256), 0, stream,
                       wsTri, wsMask, out);
}

// Round 6
// 65.329 us; speedup vs baseline: 1.3934x; 1.0580x over previous
//
#include <hip/hip_runtime.h>

#pragma clang fp contract(off)

namespace {

constexpr int kT  = 2;
constexpr int kR  = 2;
constexpr int kP  = 2048;
constexpr int kNT = 400;
constexpr float kEps   = 1e-6f;
constexpr float kHitTh = 0.999f;

constexpr int kNumPaths  = kT * kR * kP;      // 8192
constexpr int kFpFloats  = kNumPaths * 12;    // 98304
constexpr int kObjFloats = kNumPaths * 4;     // 32768

constexpr int kPathsPerBlock = 64;
constexpr int kBlocks = kNumPaths / kPathsPerBlock;   // 128

__device__ inline void cross3(const float a[3], const float b[3], float o[3]) {
    o[0] = a[1] * b[2] - a[2] * b[1];
    o[1] = a[2] * b[0] - a[0] * b[2];
    o[2] = a[0] * b[1] - a[1] * b[0];
}
__device__ inline float dot3(const float a[3], const float b[3]) {
    return a[0] * b[0] + a[1] * b[1] + a[2] * b[2];
}

// Single fused kernel: block owns 64 paths.
// Phase 1: wave0 lanes do per-path setup (image method + mask1/2), waves 1-3
//          stage all triangles (v0,e1,e2) into LDS.
// Phase 2: all 4 waves round-robin the survivor queue; wave-per-path
//          Moller-Trumbore with uniform __any early exit.
__global__ __launch_bounds__(256)
void fused_kernel(const float* __restrict__ tx,
                  const float* __restrict__ rx,
                  const float* __restrict__ verts,
                  const float* __restrict__ normals,
                  const int*   __restrict__ tris,
                  const int*   __restrict__ pcs,
                  float*       __restrict__ out)
{
    __shared__ float sV0[kNT][3];
    __shared__ float sE1[kNT][3];
    __shared__ float sE2[kNT][3];
    __shared__ float sFp[kPathsPerBlock][12];
    __shared__ int   sQueue[kPathsPerBlock];
    __shared__ int   sCount;

    const int tid = threadIdx.x;
    if (tid == 0) sCount = 0;
    __syncthreads();

    if (tid < kPathsPerBlock) {
        // ---------------- per-path setup (one path per lane of wave 0)
        const int L    = blockIdx.x * kPathsPerBlock + tid;
        const int tIdx = L / (kR * kP);
        const int rem  = L % (kR * kP);
        const int rIdx = rem / kP;
        const int p    = rem % kP;

        float fp[4][3];
        fp[0][0] = tx[3 * tIdx + 0]; fp[0][1] = tx[3 * tIdx + 1]; fp[0][2] = tx[3 * tIdx + 2];
        fp[3][0] = rx[3 * rIdx + 0]; fp[3][1] = rx[3 * rIdx + 1]; fp[3][2] = rx[3 * rIdx + 2];

        const int pcm[2] = { pcs[2 * p + 0], pcs[2 * p + 1] };

        float tv[2][3][3];
        float mn[2][3];
        #pragma unroll
        for (int m = 0; m < 2; ++m) {
            int tc = pcm[m];
            int i0 = tris[3 * tc + 0], i1 = tris[3 * tc + 1], i2 = tris[3 * tc + 2];
            #pragma unroll
            for (int c = 0; c < 3; ++c) {
                tv[m][0][c] = verts[3 * i0 + c];
                tv[m][1][c] = verts[3 * i1 + c];
                tv[m][2][c] = verts[3 * i2 + c];
                mn[m][c]    = normals[3 * tc + c];
            }
        }

        // ---- image method (exact reference op order) ----
        float img0[3], img1[3];
        {
            float diff[3];
            #pragma unroll
            for (int c = 0; c < 3; ++c) diff[c] = fp[0][c] - tv[0][0][c];
            float d0 = dot3(diff, mn[0]);
            #pragma unroll
            for (int c = 0; c < 3; ++c) img0[c] = fp[0][c] - 2.0f * d0 * mn[0][c];
            #pragma unroll
            for (int c = 0; c < 3; ++c) diff[c] = img0[c] - tv[1][0][c];
            float d1 = dot3(diff, mn[1]);
            #pragma unroll
            for (int c = 0; c < 3; ++c) img1[c] = img0[c] - 2.0f * d1 * mn[1][c];
        }
        {
            float u[3], w[3];
            #pragma unroll
            for (int c = 0; c < 3; ++c) u[c] = fp[3][c] - img1[c];
            #pragma unroll
            for (int c = 0; c < 3; ++c) w[c] = tv[1][0][c] - img1[c];
            float tpar = dot3(w, mn[1]) / dot3(u, mn[1]);
            #pragma unroll
            for (int c = 0; c < 3; ++c) fp[2][c] = img1[c] + tpar * u[c];
            #pragma unroll
            for (int c = 0; c < 3; ++c) u[c] = fp[2][c] - img0[c];
            #pragma unroll
            for (int c = 0; c < 3; ++c) w[c] = tv[0][0][c] - img0[c];
            tpar = dot3(w, mn[0]) / dot3(u, mn[0]);
            #pragma unroll
            for (int c = 0; c < 3; ++c) fp[1][c] = img0[c] + tpar * u[c];
        }

        // ---- mask1: containment ----
        bool mask1 = true;
        #pragma unroll
        for (int m = 0; m < 2; ++m) {
            float u0[3], u1[3], u2[3], n0[3], n1[3], n2[3];
            #pragma unroll
            for (int c = 0; c < 3; ++c) {
                u0[c] = tv[m][0][c] - fp[1 + m][c];
                u1[c] = tv[m][1][c] - fp[1 + m][c];
                u2[c] = tv[m][2][c] - fp[1 + m][c];
            }
            cross3(u0, u1, n0); cross3(u1, u2, n1); cross3(u2, u0, n2);
            float d01 = dot3(n0, n1), d12 = dot3(n1, n2), d20 = dot3(n2, n0);
            mask1 = mask1 && (d01 >= 0.0f) && (d12 >= 0.0f) && (d20 >= 0.0f);
        }

        // ---- mask2: consecutive same side ----
        bool mask2 = true;
        #pragma unroll
        for (int m = 0; m < 2; ++m) {
            float a[3], b[3];
            #pragma unroll
            for (int c = 0; c < 3; ++c) {
                a[c] = fp[m][c]     - tv[m][0][c];
                b[c] = fp[m + 2][c] - tv[m][0][c];
            }
            float dp = dot3(a, mn[m]);
            float dn = dot3(b, mn[m]);
            mask2 = mask2 && (dp * dn >= 0.0f);
        }

        // ---- outputs: full_paths + objects (always), mask=0 for failures
        float* fpOut = out + (size_t)L * 12;
        #pragma unroll
        for (int pt = 0; pt < 4; ++pt)
            #pragma unroll
            for (int c = 0; c < 3; ++c) {
                fpOut[pt * 3 + c] = fp[pt][c];
                sFp[tid][pt * 3 + c] = fp[pt][c];
            }
        float* objOut = out + kFpFloats + (size_t)L * 4;
        objOut[0] = (float)tIdx;
        objOut[1] = (float)pcm[0];
        objOut[2] = (float)pcm[1];
        objOut[3] = (float)rIdx;

        if (mask1 && mask2) {
            int slot = atomicAdd(&sCount, 1);
            sQueue[slot] = tid;
        } else {
            out[kFpFloats + kObjFloats + L] = 0.0f;
        }
    } else {
        // ---------------- triangle staging (waves 1-3: 192 threads)
        for (int j = tid - kPathsPerBlock; j < kNT; j += 256 - kPathsPerBlock) {
            int i0 = tris[3 * j + 0], i1 = tris[3 * j + 1], i2 = tris[3 * j + 2];
            float ax = verts[3 * i0 + 0], ay = verts[3 * i0 + 1], az = verts[3 * i0 + 2];
            float bx = verts[3 * i1 + 0], by = verts[3 * i1 + 1], bz = verts[3 * i1 + 2];
            float cx = verts[3 * i2 + 0], cy = verts[3 * i2 + 1], cz = verts[3 * i2 + 2];
            sV0[j][0] = ax;      sV0[j][1] = ay;      sV0[j][2] = az;
            sE1[j][0] = bx - ax; sE1[j][1] = by - ay; sE1[j][2] = bz - az;
            sE2[j][0] = cx - ax; sE2[j][1] = cy - ay; sE2[j][2] = cz - az;
        }
    }
    __syncthreads();

    // ---------------- phase 2: survivors only, one wave per survivor
    const int wave = tid >> 6;
    const int lane = tid & 63;
    const int cnt  = sCount;

    for (int k = wave; k < cnt; k += 4) {
        const int pl = sQueue[k];
        const int L  = blockIdx.x * kPathsPerBlock + pl;

        float pquad[4][3];
        #pragma unroll
        for (int pt = 0; pt < 4; ++pt)
            #pragma unroll
            for (int c = 0; c < 3; ++c)
                pquad[pt][c] = sFp[pl][pt * 3 + c];   // broadcast reads

        bool anyhit = false;
        #pragma unroll
        for (int s = 0; s < 3; ++s) {
            if (anyhit) break;
            float ro[3], rd[3];
            #pragma unroll
            for (int c = 0; c < 3; ++c) {
                ro[c] = pquad[s][c];
                rd[c] = pquad[s + 1][c] - pquad[s][c];
            }
            for (int jb = 0; jb < 7; ++jb) {
                const int j = jb * 64 + lane;
                const bool valid = (j < kNT);
                const int jj = valid ? j : 0;
                float v0[3] = { sV0[jj][0], sV0[jj][1], sV0[jj][2] };
                float e1[3] = { sE1[jj][0], sE1[jj][1], sE1[jj][2] };
                float e2[3] = { sE2[jj][0], sE2[jj][1], sE2[jj][2] };
                float h[3]; cross3(rd, e2, h);
                float a = dot3(e1, h);
                float f = 1.0f / a;
                float sv[3];
                #pragma unroll
                for (int c = 0; c < 3; ++c) sv[c] = ro[c] - v0[c];
                float uu = f * dot3(sv, h);
                float q[3]; cross3(sv, e1, q);
                float vv = f * dot3(rd, q);
                float tt = f * dot3(e2, q);
                bool hit = valid
                        && (fabsf(a) > kEps) && (uu >= 0.0f) && (uu <= 1.0f)
                        && (vv >= 0.0f) && (uu + vv <= 1.0f)
                        && (tt > kEps) && (tt < kHitTh);
                if (__any(hit ? 1 : 0)) { anyhit = true; break; }
            }
        }

        if (lane == 0) {
            out[kFpFloats + kObjFloats + L] = anyhit ? 0.0f : 1.0f;
        }
    }
}

} // namespace

extern "C" void kernel_launch(void* const* d_in, const int* in_sizes, int n_in,
                              void* d_out, int out_size, void* d_ws, size_t ws_size,
                              hipStream_t stream)
{
    const float* tx      = (const float*)d_in[0];
    const float* rx      = (const float*)d_in[1];
    const float* verts   = (const float*)d_in[2];
    const float* normals = (const float*)d_in[3];
    const int*   tris    = (const int*)d_in[4];
    const int*   pcs     = (const int*)d_in[5];
    float* out = (float*)d_out;

    hipLaunchKernelGGL(fused_kernel, dim3(kBlocks), dim3(256), 0, stream,
                       tx, rx, verts, normals, tris, pcs, out);
}